// Round 4
// baseline (511.559 us; speedup 1.0000x reference)
//
#include <hip/hip_runtime.h>

#define Bn 8
#define Nn 4096
#define Pn 4096
#define Kn 32
#define Cn 128

using float4v = __attribute__((ext_vector_type(4))) float;
using short8  = __attribute__((ext_vector_type(8))) short;

__device__ __forceinline__ unsigned short bf16b(float f) {
  union { float f; unsigned u; } v; v.f = f;
  unsigned r = v.u + 0x7FFFu + ((v.u >> 16) & 1u);   // round-nearest-even
  return (unsigned short)(r >> 16);
}

// ---------------------------------------------------------------------------
// prep: WlT[n][k] = bf16(Wl[k][n])   (2048x128 -> 128x2048), 16 blocks
// ---------------------------------------------------------------------------
__global__ __launch_bounds__(256) void prep_wl(const float* __restrict__ Wl,
                                               unsigned short* __restrict__ WlT) {
  __shared__ unsigned short tile[128 * 130];
  const int t = threadIdx.x, blk = blockIdx.x;
#pragma unroll
  for (int i = 0; i < 64; ++i) {
    int idx = i * 256 + t;
    int kl = idx >> 7, n = idx & 127;
    tile[n * 130 + kl] = bf16b(Wl[(size_t)(blk * 128 + kl) * 128 + n]);
  }
  __syncthreads();
#pragma unroll
  for (int i = 0; i < 64; ++i) {
    int idx = i * 256 + t;
    int n = idx >> 7, kl = idx & 127;
    WlT[(size_t)n * 2048 + blk * 128 + kl] = tile[n * 130 + kl];
  }
}

// ---------------------------------------------------------------------------
// fused: per-wave 16 points end-to-end; M lives only in an 8 KB wave-private
// LDS slab per c-tile. Zero barriers in the main loop.
//   per ct (8 x 16 channels):
//     stage1: per point: gather B-frag (8 ushort hi-half loads, full-line per
//             q-group), MFMA vs resident weight A-frag, swizzled slab write
//     stage2: 8 k-chunks x 8 n-tiles MFMA; A from slab (b128, 2-way free),
//             B from WlT global (same addrs across all waves -> L1/L2 bcast)
// ---------------------------------------------------------------------------
__global__ __launch_bounds__(256, 2) void fused(
    const float* __restrict__ points, const float* __restrict__ lc,
    const int* __restrict__ nl, const int* __restrict__ didx,
    const float* __restrict__ Ww, const float* __restrict__ bwv,
    const unsigned short* __restrict__ WlT, const float* __restrict__ blv,
    float* __restrict__ xout, float* __restrict__ gacc) {
  __shared__ unsigned short slab[4 * 16 * 256];   // 32 KB: wave -> 16 rows x 512 B
  __shared__ float red[4][256];                   // 4 KB stats staging

  const int t = threadIdx.x, lane = t & 63, wave = t >> 6;
  const int l15 = lane & 15, q = lane >> 4;
  const int bidx = blockIdx.x & 7;                // XCD-affine batch
  const int ptile = blockIdx.x >> 3;
  const int pw0 = ptile * 64 + wave * 16;         // wave's 16 points
  const int db = didx[bidx];
  const unsigned short* __restrict__ phi =
      (const unsigned short*)(points + (size_t)db * Nn * Cn);
  const int* __restrict__ nlb = nl + ((size_t)db * Pn + pw0) * Kn + q * 8;

  // ---- weight A-frags for 16 points, resident in VGPRs --------------------
  const float Ww0 = Ww[l15], Ww1 = Ww[16 + l15], Ww2 = Ww[32 + l15];
  const float bw0 = bwv[l15];
  short8 afrag[16];
#pragma unroll
  for (int pi = 0; pi < 16; ++pi) {
    const float* __restrict__ lcp =
        lc + (((size_t)db * Pn + pw0 + pi) * Kn + q * 8) * 3;
    float la[24];
#pragma unroll
    for (int v = 0; v < 6; ++v) *(float4v*)&la[v * 4] = *(const float4v*)(lcp + v * 4);
#pragma unroll
    for (int j = 0; j < 8; ++j) {
      float w = bw0 + la[3 * j] * Ww0 + la[3 * j + 1] * Ww1 + la[3 * j + 2] * Ww2;
      afrag[pi][j] = (short)bf16b(w);
    }
  }

  float4v acc[8];
#pragma unroll
  for (int nt = 0; nt < 8; ++nt) acc[nt] = (float4v){0.f, 0.f, 0.f, 0.f};

  unsigned short* __restrict__ myslab = slab + wave * 4096;   // ushort units
  const unsigned wchunkbase = (unsigned)(l15 * 2 + (q >> 1));
  const unsigned whalf = (unsigned)((q & 1) * 4);
  const unsigned short* __restrict__ wbase = WlT + (size_t)l15 * 2048 + q * 8;

  for (int ct = 0; ct < 8; ++ct) {
    const unsigned cb = (unsigned)(ct * 32 + l15 * 2 + 1);   // hi half of f32
    // ---- stage 1: fill slab for this c-tile -------------------------------
#pragma unroll
    for (int pi = 0; pi < 16; ++pi) {
      int nk[8];
      *(int4*)&nk[0] = *(const int4*)(nlb + pi * Kn);
      *(int4*)&nk[4] = *(const int4*)(nlb + pi * Kn + 4);
      short8 bfv;
#pragma unroll
      for (int j = 0; j < 8; ++j)
        bfv[j] = (short)phi[((unsigned)nk[j] << 8) + cb];
      float4v d = {0.f, 0.f, 0.f, 0.f};
      d = __builtin_amdgcn_mfma_f32_16x16x32_bf16(afrag[pi], bfv, d, 0, 0, 0);
      ushort4 u;
      u.x = bf16b(d[0]); u.y = bf16b(d[1]); u.z = bf16b(d[2]); u.w = bf16b(d[3]);
      const unsigned chunk = wchunkbase ^ (unsigned)pi;
      *(ushort4*)&myslab[pi * 256 + chunk * 8 + whalf] = u;
    }
    // ---- stage 2: this c-tile's K-chunk vs WlT ----------------------------
    const unsigned short* __restrict__ bct = wbase + ct * 256;
#pragma unroll
    for (int kc = 0; kc < 8; ++kc) {
      const unsigned achunk = ((unsigned)(kc * 4 + q)) ^ (unsigned)l15;
      short8 a = *(const short8*)&myslab[l15 * 256 + achunk * 8];
#pragma unroll
      for (int nt = 0; nt < 8; ++nt) {
        short8 bf = *(const short8*)(bct + (size_t)nt * 16 * 2048 + kc * 32);
        acc[nt] = __builtin_amdgcn_mfma_f32_16x16x32_bf16(a, bf, acc[nt], 0, 0, 0);
      }
    }
  }

  // ---- epilogue: bias, transposed store (B,C,P), block-reduced stats ------
  const int pst = pw0 + q * 4;
#pragma unroll
  for (int nt = 0; nt < 8; ++nt) {
    const int ch = nt * 16 + l15;
    const float bb = blv[ch];
    float4v o;
    float s = 0.f, sq2 = 0.f;
#pragma unroll
    for (int r = 0; r < 4; ++r) {
      float v = acc[nt][r] + bb; o[r] = v; s += v; sq2 += v * v;
    }
    *(float4v*)(xout + ((size_t)bidx * Cn + ch) * Pn + pst) = o;
    s += __shfl_xor(s, 16); s += __shfl_xor(s, 32);
    sq2 += __shfl_xor(sq2, 16); sq2 += __shfl_xor(sq2, 32);
    if (lane < 16) { red[wave][ch] = s; red[wave][128 + ch] = sq2; }
  }
  __syncthreads();
  const float v = red[0][t] + red[1][t] + red[2][t] + red[3][t];
  atomicAdd(&gacc[t], v);
}

// ---------------------------------------------------------------------------
// finalize: layernorm (per-channel over B*P) + relu, in place on x chunk
// ---------------------------------------------------------------------------
__global__ __launch_bounds__(256) void finalize_ln(float* __restrict__ x,
                                                   const float* __restrict__ gacc,
                                                   const float* __restrict__ gamma,
                                                   const float* __restrict__ beta) {
  const int idx = blockIdx.x * 256 + threadIdx.x;
  const int fi = idx * 4;
  const int c = (fi >> 12) & 127;
  const float inv = 1.f / 32768.f;
  const float mean = gacc[c] * inv;
  const float var = gacc[128 + c] * inv - mean * mean;
  const float scale = rsqrtf(var + 1e-5f) * gamma[c];
  const float shift = beta[c] - mean * scale;
  float4v v = *(float4v*)(x + fi);
#pragma unroll
  for (int r = 0; r < 4; ++r) v[r] = fmaxf(v[r] * scale + shift, 0.f);
  *(float4v*)(x + fi) = v;
}

extern "C" void kernel_launch(void* const* d_in, const int* in_sizes, int n_in,
                              void* d_out, int out_size, void* d_ws, size_t ws_size,
                              hipStream_t stream) {
  const float* xyz    = (const float*)d_in[0];
  const float* points = (const float*)d_in[1];
  const float* lc     = (const float*)d_in[2];
  const int*   nl     = (const int*)d_in[3];
  const int*   didx   = (const int*)d_in[4];
  const float* Ww     = (const float*)d_in[5];
  const float* bw     = (const float*)d_in[6];
  const float* Wl     = (const float*)d_in[7];
  const float* bl     = (const float*)d_in[8];
  const float* gamma  = (const float*)d_in[9];
  const float* beta   = (const float*)d_in[10];

  float* out  = (float*)d_out;
  float* xout = out + (size_t)Bn * Pn * 3;                   // x chunk (B,C,P)
  unsigned short* WlT = (unsigned short*)d_ws;               // 512 KB
  float* gacc = (float*)((char*)d_ws + (size_t)512 * 1024);  // 1 KB

  hipMemcpyAsync(out, xyz, (size_t)Bn * Pn * 3 * sizeof(float),
                 hipMemcpyDeviceToDevice, stream);
  hipMemsetAsync(gacc, 0, 256 * sizeof(float), stream);
  prep_wl<<<16, 256, 0, stream>>>(Wl, WlT);
  fused<<<512, 256, 0, stream>>>(points, lc, nl, didx, Ww, bw, WlT, bl,
                                 xout, gacc);
  finalize_ln<<<4096, 256, 0, stream>>>(xout, gacc, gamma, beta);
}

// Round 6
// 244.653 us; speedup vs baseline: 2.0910x; 2.0910x over previous
//
#include <hip/hip_runtime.h>

#define Bn 8
#define Nn 4096
#define Pn 4096
#define Kn 32
#define Cn 128

using float4v = __attribute__((ext_vector_type(4))) float;
using short8  = __attribute__((ext_vector_type(8))) short;

__device__ __forceinline__ unsigned short bf16b(float f) {
  union { float f; unsigned u; } v; v.f = f;
  unsigned r = v.u + 0x7FFFu + ((v.u >> 16) & 1u);   // round-nearest-even
  return (unsigned short)(r >> 16);
}

__device__ __forceinline__ unsigned pk_bf16(float a, float b) {
  return (unsigned)bf16b(a) | ((unsigned)bf16b(b) << 16);
}

__device__ __forceinline__ void gld_lds16(const void* g, void* l) {
  __builtin_amdgcn_global_load_lds(
      (const __attribute__((address_space(1))) unsigned int*)g,
      (__attribute__((address_space(3))) unsigned int*)l, 16, 0, 0);
}

// ---------------------------------------------------------------------------
// prep: WlT[n][k] = bf16(Wl[k][n])   (2048x128 -> 128x2048), 16 blocks
// ---------------------------------------------------------------------------
__global__ __launch_bounds__(256) void prep_wl(const float* __restrict__ Wl,
                                               unsigned short* __restrict__ WlT) {
  __shared__ unsigned short tile[128 * 130];
  const int t = threadIdx.x, blk = blockIdx.x;
#pragma unroll
  for (int i = 0; i < 64; ++i) {
    int idx = i * 256 + t;
    int kl = idx >> 7, n = idx & 127;
    tile[n * 130 + kl] = bf16b(Wl[(size_t)(blk * 128 + kl) * 128 + n]);
  }
  __syncthreads();
#pragma unroll
  for (int i = 0; i < 64; ++i) {
    int idx = i * 256 + t;
    int n = idx >> 7, kl = idx & 127;
    WlT[(size_t)n * 2048 + blk * 128 + kl] = tile[n * 130 + kl];
  }
}

// ---------------------------------------------------------------------------
// stage1: coalesced row-gather + wave-private LDS transpose.
// Cross-lane slab write->read within a wave: HW DS ops are in-order per
// wave, but the COMPILER sees no dependence — wave_barrier() fences block
// instruction motion across the transpose boundaries (round-5 bug fix).
// ---------------------------------------------------------------------------
__global__ __launch_bounds__(256) void stage1(
    const float* __restrict__ points, const float* __restrict__ lc,
    const int* __restrict__ nl, const int* __restrict__ didx,
    const float* __restrict__ Ww, const float* __restrict__ bwv,
    unsigned short* __restrict__ Mglob) {
  __shared__ unsigned short slab4[4][32 * 128];   // 8 KB per wave

  const int t = threadIdx.x;
  const int lane = t & 63, wave = t >> 6;
  const int l15 = lane & 15, q = lane >> 4;
  const int b = blockIdx.x & 7;          // XCD-affine batch
  const int tile = blockIdx.x >> 3;      // 0..255, 16 points per block
  const int db = didx[b];
  const float* __restrict__ pbat = points + (size_t)db * Nn * Cn;
  unsigned short* __restrict__ slab = slab4[wave];
  const float Ww0 = Ww[l15], Ww1 = Ww[16 + l15], Ww2 = Ww[32 + l15];
  const float bw0 = bwv[l15];

  for (int pi = 0; pi < 4; ++pi) {
    const int p = tile * 16 + wave * 4 + pi;
    const size_t pk = (size_t)(db * Pn + p) * Kn;
    // all 32 neighbor ids (broadcast int4 loads, constant-indexed -> VGPRs)
    int nk[32];
    const int4* __restrict__ nl4 = (const int4*)(nl + pk);
#pragma unroll
    for (int i = 0; i < 8; ++i) *(int4*)&nk[i * 4] = nl4[i];
    // weight A-frag: A[m=w=l15][k=q*8+j]
    const float* __restrict__ lcp = lc + (pk + q * 8) * 3;
    float la[24];
#pragma unroll
    for (int v = 0; v < 6; ++v) *(float4v*)&la[v * 4] = *(const float4v*)(lcp + v * 4);
    short8 af;
#pragma unroll
    for (int j = 0; j < 8; ++j) {
      float w = bw0 + la[3 * j] * Ww0 + la[3 * j + 1] * Ww1 + la[3 * j + 2] * Ww2;
      af[j] = (short)bf16b(w);
    }
    // fence: prior iteration's slab reads must not sink below these writes
    __builtin_amdgcn_wave_barrier();
    // coalesced row loads -> rotated slab [k][c]
#pragma unroll
    for (int r = 0; r < 32; ++r) {
      const float2 v = ((const float2*)(pbat + (size_t)nk[r] * Cn))[lane];
      const unsigned idx = r * 128 + ((lane * 2 + (r >> 3) * 16) & 127);
      *(unsigned*)&slab[idx] = pk_bf16(v.x, v.y);
    }
    // fence: slab reads below must not hoist above the writes
    __builtin_amdgcn_wave_barrier();
    // frags + MFMA + M-store
    unsigned short* __restrict__ mrow = Mglob + ((size_t)b * Pn + p) * 2048;
#pragma unroll
    for (int ct = 0; ct < 8; ++ct) {
      const int coff = (ct * 16 + l15 + q * 16) & 127;
      short8 bfv;
#pragma unroll
      for (int j = 0; j < 8; ++j)
        bfv[j] = (short)slab[(q * 8 + j) * 128 + coff];
      float4v d = {0.f, 0.f, 0.f, 0.f};
      d = __builtin_amdgcn_mfma_f32_16x16x32_bf16(af, bfv, d, 0, 0, 0);
      ushort4 u;
      u.x = bf16b(d[0]); u.y = bf16b(d[1]); u.z = bf16b(d[2]); u.w = bf16b(d[3]);
      *(ushort4*)&mrow[(ct * 16 + l15) * 16 + q * 4] = u;
    }
    __builtin_amdgcn_wave_barrier();
  }
}

// ---------------------------------------------------------------------------
// stage2: Y(32768x128) = M(32768x2048) @ Wl(2048x128).
// 1024 blocks, 32 rows x 128 n; BK=64 staged via global_load_lds(16B) with
// XOR chunk swizzle; wave = 32 rows x 32 n (8 b128 frag reads / kk).
// ---------------------------------------------------------------------------
__global__ __launch_bounds__(256) void stage2(
    const unsigned short* __restrict__ Mglob,
    const unsigned short* __restrict__ WlT, const float* __restrict__ blv,
    float* __restrict__ xout, float* __restrict__ gacc) {
  __shared__ unsigned short As[32 * 64];    // 4 KB
  __shared__ unsigned short Bs[128 * 64];   // 16 KB
  __shared__ float red[256];

  const int t = threadIdx.x, lane = t & 63, wave = t >> 6;
  const int l15 = lane & 15, q = lane >> 4;
  const int lr = lane >> 3, lchk = lane & 7;
  const int bidx = blockIdx.x & 7;                 // XCD-affine batch
  const int pt0 = (blockIdx.x >> 3) * 32;
  const size_t row0 = (size_t)bidx * Pn + pt0;

  float4v acc[2][2];
#pragma unroll
  for (int rt = 0; rt < 2; ++rt)
#pragma unroll
    for (int nt = 0; nt < 2; ++nt) acc[rt][nt] = (float4v){0.f, 0.f, 0.f, 0.f};

  for (int kk = 0; kk < 32; ++kk) {
    const int k0 = kk * 64;
    // A: wave stages rows [8w, 8w+8)  (1 KB per inst, swizzle key row&7=lr)
    gld_lds16(Mglob + (row0 + wave * 8 + lr) * 2048 + k0 + (lchk ^ lr) * 8,
              &As[wave * 8 * 64]);
    // B: wave stages n in [32w, 32w+32)
#pragma unroll
    for (int it = 0; it < 4; ++it) {
      const int n = wave * 32 + it * 8 + lr;
      gld_lds16(WlT + (size_t)n * 2048 + k0 + (lchk ^ lr) * 8,
                &Bs[(wave * 32 + it * 8) * 64]);
    }
    __syncthreads();
#pragma unroll
    for (int ks = 0; ks < 2; ++ks) {
      short8 a[2], bq[2];
#pragma unroll
      for (int rt = 0; rt < 2; ++rt) {
        const int row = rt * 16 + l15;
        a[rt] = *(const short8*)&As[row * 64 + (((ks * 4 + q) ^ (row & 7)) << 3)];
      }
#pragma unroll
      for (int nt = 0; nt < 2; ++nt) {
        const int n = wave * 32 + nt * 16 + l15;
        bq[nt] = *(const short8*)&Bs[n * 64 + (((ks * 4 + q) ^ (n & 7)) << 3)];
      }
#pragma unroll
      for (int rt = 0; rt < 2; ++rt)
#pragma unroll
        for (int nt = 0; nt < 2; ++nt)
          acc[rt][nt] = __builtin_amdgcn_mfma_f32_16x16x32_bf16(a[rt], bq[nt],
                                                                acc[rt][nt], 0, 0, 0);
    }
    __syncthreads();
  }

  // epilogue: bias, transposed store (B,C,P), disjoint per-wave channel stats
#pragma unroll
  for (int nt = 0; nt < 2; ++nt) {
    const int ch = wave * 32 + nt * 16 + l15;
    const float bb = blv[ch];
    float s = 0.f, sq = 0.f;
#pragma unroll
    for (int rt = 0; rt < 2; ++rt) {
      float4v o;
#pragma unroll
      for (int r = 0; r < 4; ++r) {
        float v = acc[rt][nt][r] + bb; o[r] = v; s += v; sq += v * v;
      }
      *(float4v*)(xout + ((size_t)bidx * Cn + ch) * Pn + pt0 + rt * 16 + q * 4) = o;
    }
    s += __shfl_xor(s, 16); s += __shfl_xor(s, 32);
    sq += __shfl_xor(sq, 16); sq += __shfl_xor(sq, 32);
    if (lane < 16) { red[ch] = s; red[128 + ch] = sq; }
  }
  __syncthreads();
  atomicAdd(&gacc[t], red[t]);
}

// ---------------------------------------------------------------------------
// finalize: layernorm (per-channel over B*P) + relu, in place on x chunk
// ---------------------------------------------------------------------------
__global__ __launch_bounds__(256) void finalize_ln(float* __restrict__ x,
                                                   const float* __restrict__ gacc,
                                                   const float* __restrict__ gamma,
                                                   const float* __restrict__ beta) {
  const int idx = blockIdx.x * 256 + threadIdx.x;
  const int fi = idx * 4;
  const int c = (fi >> 12) & 127;
  const float inv = 1.f / 32768.f;
  const float mean = gacc[c] * inv;
  const float var = gacc[128 + c] * inv - mean * mean;
  const float scale = rsqrtf(var + 1e-5f) * gamma[c];
  const float shift = beta[c] - mean * scale;
  float4v v = *(float4v*)(x + fi);
#pragma unroll
  for (int r = 0; r < 4; ++r) v[r] = fmaxf(v[r] * scale + shift, 0.f);
  *(float4v*)(x + fi) = v;
}

extern "C" void kernel_launch(void* const* d_in, const int* in_sizes, int n_in,
                              void* d_out, int out_size, void* d_ws, size_t ws_size,
                              hipStream_t stream) {
  const float* xyz    = (const float*)d_in[0];
  const float* points = (const float*)d_in[1];
  const float* lc     = (const float*)d_in[2];
  const int*   nl     = (const int*)d_in[3];
  const int*   didx   = (const int*)d_in[4];
  const float* Ww     = (const float*)d_in[5];
  const float* bw     = (const float*)d_in[6];
  const float* Wl     = (const float*)d_in[7];
  const float* bl     = (const float*)d_in[8];
  const float* gamma  = (const float*)d_in[9];
  const float* beta   = (const float*)d_in[10];

  float* out  = (float*)d_out;
  float* xout = out + (size_t)Bn * Pn * 3;                       // x chunk (B,C,P)
  unsigned short* WlT = (unsigned short*)d_ws;                   // 512 KB
  float* gacc = (float*)((char*)d_ws + (size_t)512 * 1024);      // 1 KB
  unsigned short* Mglob =
      (unsigned short*)((char*)d_ws + (size_t)1024 * 1024);      // 128 MB

  hipMemcpyAsync(out, xyz, (size_t)Bn * Pn * 3 * sizeof(float),
                 hipMemcpyDeviceToDevice, stream);
  hipMemsetAsync(gacc, 0, 256 * sizeof(float), stream);
  prep_wl<<<16, 256, 0, stream>>>(Wl, WlT);
  stage1<<<2048, 256, 0, stream>>>(points, lc, nl, didx, Ww, bw, Mglob);
  stage2<<<1024, 256, 0, stream>>>(Mglob, WlT, bl, xout, gacc);
  finalize_ln<<<4096, 256, 0, stream>>>(xout, gacc, gamma, beta);
}